// Round 8
// baseline (40.059 us; speedup 1.0000x reference)
//
#include <hip/hip_runtime.h>
#include <hip/hip_bf16.h>

// B=32, IN_N=8192, POSE=64, M=8, NH=32, S2=256, HID=256, OUT_N=64
//
// Decomposition:
//  S[b,r][e]   = sum_{p<64} (CP[b, p*128+r] @ WC[p*128+r])[e],  r in [0,128), e=m1*8+m2
//              = 8x8x512 GEMM per (b,r) -> MFMA 16x16x32, 2 r's per wave (diag blocks),
//              p-sum quarter-split for occupancy: S4[quarter][b][j]
//  F[r,e,q]    = sum_{hh<4} E_proj[r>>2, (r&3)*64+e, hh*64+q]
//  pooled[b,q] = (1/64) sum_j (sum_qt S4[qt,b,j]) * F[j,q]
//     pool kernel blocks over j-chunks of 128: F read EXACTLY ONCE (2 MB),
//     S staged in LDS for all 32 b's, broadcast reads.
//  out[b,o,m1,m2] = sum_k (pooled[b,m1*8+k]+rel[m1*8+k]) * w_next[o,k,m2]

typedef short short8_t __attribute__((ext_vector_type(8)));
typedef float f32x4_t __attribute__((ext_vector_type(4)));
typedef int   int4_t  __attribute__((ext_vector_type(4)));

__device__ __forceinline__ short f2bf(float f) {
    union { float f; unsigned u; } v; v.f = f;
    unsigned r = v.u + 0x7FFFu + ((v.u >> 16) & 1u);   // RNE
    return (short)(r >> 16);
}

// packed f32x2 -> bf16x2 via HW instruction (no builtin on gfx950; m240)
__device__ __forceinline__ int cvt_pk(float x, float y) {
    int r;
    asm("v_cvt_pk_bf16_f32 %0, %1, %2" : "=v"(r) : "v"(x), "v"(y));
    return r;
}

// ---------- Kernel PREP: fused {WCf pack, E-fold} ----------
__global__ void k_prep(const float* __restrict__ WC, short* __restrict__ WCf,
                       const float* __restrict__ E, float* __restrict__ F) {
    if (blockIdx.x < 256) {
        int t   = blockIdx.x * 256 + threadIdx.x;  // [0, 65536)
        int l   = t & 63;
        int pc  = (t >> 6) & 15;
        int rp  = t >> 10;
        int lhi = l >> 4;
        int j   = l & 15;
        int row = (pc * 4 + lhi) * 128 + rp * 2 + (j >> 3);
        const float* src = WC + ((size_t)row << 6) + (j & 7);
        short8_t o;
        #pragma unroll
        for (int k = 0; k < 8; ++k) o[k] = f2bf(src[k * 8]);
        ((short8_t*)WCf)[t] = o;
    } else {
        int idx = ((blockIdx.x - 256) * 256 + threadIdx.x) * 4;  // [0, 524288)
        int q   = idx & 63;
        int row = idx >> 6;
        int r   = row >> 6;
        int e   = row & 63;
        int nh  = r >> 2;
        int s2  = ((r & 3) << 6) + e;
        const float* base = E + (((size_t)nh * 256 + s2) << 8) + q;
        float4 s0 = *(const float4*)(base);
        float4 s1 = *(const float4*)(base + 64);
        float4 s2v = *(const float4*)(base + 128);
        float4 s3 = *(const float4*)(base + 192);
        float4 o;
        o.x = s0.x + s1.x + s2v.x + s3.x;
        o.y = s0.y + s1.y + s2v.y + s3.y;
        o.z = s0.z + s1.z + s2v.z + s3.z;
        o.w = s0.w + s1.w + s2v.w + s3.w;
        *(float4*)(F + idx) = o;
    }
}

// ---------- Kernel SMAT: S via MFMA, p quarter-split ----------
// grid (64, 32): gx -> (rpg, quarter), gy -> b. 4 waves/block, 1 rp each.
__global__ void k_smat(const float* __restrict__ CP, const short* __restrict__ WCf,
                       float* __restrict__ S4) {
    int b    = blockIdx.y;
    int gx   = blockIdx.x;
    int quarter = gx & 3;
    int rpg  = gx >> 2;              // [0,16)
    int w = threadIdx.x >> 6;
    int l = threadIdx.x & 63;
    int rp = rpg * 4 + w;            // [0,64)
    int r0 = rp * 2;

    int i16   = l & 15;
    int r_sel = i16 >> 3;
    int m1    = i16 & 7;
    int lhi   = l >> 4;              // [0,4)

    const float* cp_base = CP + ((size_t)b << 19) + ((size_t)(r0 + r_sel) << 6) + m1 * 8;
    const short8_t* wf   = (const short8_t*)WCf + (size_t)rp * 1024 + (quarter * 4) * 64 + l;

    f32x4_t acc = {0.f, 0.f, 0.f, 0.f};
    #pragma unroll
    for (int c = 0; c < 4; ++c) {
        int p = (quarter * 4 + c) * 4 + lhi;
        const float* a_ptr = cp_base + ((size_t)p << 13);   // p*128 rows * 64 floats
        float4 a0 = *(const float4*)(a_ptr);
        float4 a1 = *(const float4*)(a_ptr + 4);
        int4_t ai;
        ai[0] = cvt_pk(a0.x, a0.y);
        ai[1] = cvt_pk(a0.z, a0.w);
        ai[2] = cvt_pk(a1.x, a1.y);
        ai[3] = cvt_pk(a1.z, a1.w);
        acc = __builtin_amdgcn_mfma_f32_16x16x32_bf16(
            __builtin_bit_cast(short8_t, ai), wf[c * 64], acc, 0, 0, 0);
    }
    // C/D layout (m89-verified): col = lane&15, row = (lane>>4)*4 + reg
    float* Sd = S4 + ((size_t)quarter << 18) + ((size_t)b << 13);
    int col = i16;
    #pragma unroll
    for (int v = 0; v < 4; ++v) {
        int row = lhi * 4 + v;
        if (row < 8 && col < 8)
            Sd[(r0 << 6) + row * 8 + col] = acc[v];
        else if (row >= 8 && col >= 8)
            Sd[((r0 + 1) << 6) + (row - 8) * 8 + (col - 8)] = acc[v];
    }
}

// ---------- Kernel POOL: P[jc][b][q] = sum_{j in chunk} S[b,j]*F[j,q] ----------
// grid (64): jc. F read exactly once across the whole grid.
__global__ void k_pool(const float* __restrict__ S4, const float* __restrict__ F,
                       float* __restrict__ P) {
    int jc = blockIdx.x;             // [0,64), chunk of 128 j's
    int t  = threadIdx.x;

    __shared__ float S_lds[128][33]; // [j_loc][b], padded

    // Stage: thread t -> b = t>>3, jg = t&7 covers j_loc = jg*16..+15
    {
        int b  = t >> 3;
        int jg = t & 7;
        const float* base = S4 + ((size_t)b << 13) + jc * 128 + jg * 16;
        #pragma unroll
        for (int k = 0; k < 4; ++k) {
            float4 v0 = *(const float4*)(base + k * 4);
            float4 v1 = *(const float4*)(base + (1u << 18) + k * 4);
            float4 v2 = *(const float4*)(base + (2u << 18) + k * 4);
            float4 v3 = *(const float4*)(base + (3u << 18) + k * 4);
            int j0 = jg * 16 + k * 4;
            S_lds[j0 + 0][b] = v0.x + v1.x + v2.x + v3.x;
            S_lds[j0 + 1][b] = v0.y + v1.y + v2.y + v3.y;
            S_lds[j0 + 2][b] = v0.z + v1.z + v2.z + v3.z;
            S_lds[j0 + 3][b] = v0.w + v1.w + v2.w + v3.w;
        }
    }
    __syncthreads();

    // Compute: wave = b-group (bg = t>>6), lane = q. S broadcast from LDS, F coalesced.
    int q  = t & 63;
    int bg = t >> 6;                 // [0,4): b = bg*8 .. bg*8+7
    const float* Fb = F + (((size_t)jc * 128) << 6) + q;
    float acc[8] = {0.f, 0.f, 0.f, 0.f, 0.f, 0.f, 0.f, 0.f};
    #pragma unroll 4
    for (int j = 0; j < 128; ++j) {
        float f = Fb[(size_t)j << 6];
        #pragma unroll
        for (int bb = 0; bb < 8; ++bb)
            acc[bb] += S_lds[j][bg * 8 + bb] * f;
    }
    #pragma unroll
    for (int bb = 0; bb < 8; ++bb)
        P[((size_t)(jc * 32 + bg * 8 + bb) << 6) + q] = acc[bb];
}

// ---------- Kernel FINAL ----------
// grid (32): b. pooled[b,q] = (1/64)*sum_{jc<64} P[jc][b][q]; epilogue GEMM.
__global__ void k_final(const float* __restrict__ P, const float* __restrict__ rel,
                        const float* __restrict__ WN, float* __restrict__ out) {
    int b  = blockIdx.x;
    int t  = threadIdx.x;
    int q    = t & 63;
    int sgrp = t >> 6;               // [0,4): 16 jc each
    float s = 0.f;
    #pragma unroll
    for (int c = sgrp * 16; c < sgrp * 16 + 16; ++c)
        s += P[((size_t)(c * 32 + b) << 6) + q];
    __shared__ float red[4][64];
    red[sgrp][q] = s;
    __syncthreads();
    __shared__ float pool_s[64];
    if (t < 64) {
        pool_s[t] = (red[0][t] + red[1][t] + red[2][t] + red[3][t]) * (1.0f / 64.0f)
                    + rel[t];
    }
    __syncthreads();
    #pragma unroll
    for (int idx = t; idx < 4096; idx += 256) {
        int o = idx >> 6;
        int e = idx & 63;
        int m1 = e >> 3, m2 = e & 7;
        float a = 0.f;
        #pragma unroll
        for (int k = 0; k < 8; ++k)
            a += pool_s[m1 * 8 + k] * WN[o * 64 + k * 8 + m2];
        out[((size_t)b << 12) + idx] = a;
    }
}

extern "C" void kernel_launch(void* const* d_in, const int* in_sizes, int n_in,
                              void* d_out, int out_size, void* d_ws, size_t ws_size,
                              hipStream_t stream) {
    const float* current_pose = (const float*)d_in[0];  // (32, 8192, 64)
    const float* w_current    = (const float*)d_in[1];  // (1,1,8192,8,8)
    const float* w_next       = (const float*)d_in[2];  // (64,8,8)
    const float* E_proj       = (const float*)d_in[3];  // (32,256,256)
    const float* rel_embedd   = (const float*)d_in[4];  // (1,1,64)
    float* out = (float*)d_out;                         // (32,1,64,64)

    char* ws = (char*)d_ws;
    float* F   = (float*)(ws);                    // 2 MiB
    short* WCf = (short*)(ws + (2u << 20));       // 1 MiB
    float* S4  = (float*)(ws + (3u << 20));       // 4 MiB (4 x 32 x 8192)
    float* P   = (float*)(ws + (7u << 20));       // 512 KiB (64 x 32 x 64)

    // PREP: WCf pack (256 blocks) + E fold (512 blocks)
    k_prep<<<dim3(768), dim3(256), 0, stream>>>(w_current, WCf, E_proj, F);
    // SMAT: the 64 MB stream, quarter-split p (2048 blocks, 32 waves/CU)
    k_smat<<<dim3(64, 32), dim3(256), 0, stream>>>(current_pose, WCf, S4);
    // POOL: F read exactly once (2 MB), S broadcast from LDS
    k_pool<<<dim3(64), dim3(256), 0, stream>>>(S4, F, P);
    // FINAL
    k_final<<<dim3(32), dim3(256), 0, stream>>>(P, rel_embedd, w_next, out);
}

// Round 9
// 29.704 us; speedup vs baseline: 1.3486x; 1.3486x over previous
//
#include <hip/hip_runtime.h>
#include <hip/hip_bf16.h>

// B=32, IN_N=8192, POSE=64, M=8, NH=32, S2=256, HID=256, OUT_N=64
//
//  S[b,r][e]   = sum_{p<64} (CP[b, p*128+r] @ WC[p*128+r])[e],  r in [0,128), e=m1*8+m2
//              -> MFMA 16x16x32, 2 r's per wave (diag blocks), p half-split
//  F[r,e,q]    = sum_{hh<4} E_proj[r>>2, (r&3)*64+e, hh*64+q]
//  pooled[b,q] = (1/64) sum_j S[b,j] * F[j,q]
//     fused into BC: block covers (rpg j-slice of 512, half, 2 b's); each F row
//     read ONCE per block and applied to both b's  -> F L2 amp = 32 (64 MB)
//  out[b,o,m1,m2] = sum_k (pooled[b,m1*8+k]+rel[m1*8+k]) * w_next[o,k,m2]

typedef short short8_t __attribute__((ext_vector_type(8)));
typedef float f32x4_t __attribute__((ext_vector_type(4)));
typedef int   int4_t  __attribute__((ext_vector_type(4)));

__device__ __forceinline__ short f2bf(float f) {
    union { float f; unsigned u; } v; v.f = f;
    unsigned r = v.u + 0x7FFFu + ((v.u >> 16) & 1u);   // RNE
    return (short)(r >> 16);
}

// packed f32x2 -> bf16x2 via HW instruction (no builtin on gfx950; m240)
__device__ __forceinline__ int cvt_pk(float x, float y) {
    int r;
    asm("v_cvt_pk_bf16_f32 %0, %1, %2" : "=v"(r) : "v"(x), "v"(y));
    return r;
}

// ---------- Kernel PREP: fused {WCf pack, E-fold} (identical to R6) ----------
__global__ void k_prep(const float* __restrict__ WC, short* __restrict__ WCf,
                       const float* __restrict__ E, float* __restrict__ F) {
    if (blockIdx.x < 256) {
        int t   = blockIdx.x * 256 + threadIdx.x;  // [0, 65536)
        int l   = t & 63;
        int pc  = (t >> 6) & 15;
        int rp  = t >> 10;
        int lhi = l >> 4;
        int j   = l & 15;
        int row = (pc * 4 + lhi) * 128 + rp * 2 + (j >> 3);
        const float* src = WC + ((size_t)row << 6) + (j & 7);
        short8_t o;
        #pragma unroll
        for (int k = 0; k < 8; ++k) o[k] = f2bf(src[k * 8]);
        ((short8_t*)WCf)[t] = o;
    } else {
        int idx = ((blockIdx.x - 256) * 256 + threadIdx.x) * 4;  // [0, 524288)
        int q   = idx & 63;
        int row = idx >> 6;
        int r   = row >> 6;
        int e   = row & 63;
        int nh  = r >> 2;
        int s2  = ((r & 3) << 6) + e;
        const float* base = E + (((size_t)nh * 256 + s2) << 8) + q;
        float4 s0 = *(const float4*)(base);
        float4 s1 = *(const float4*)(base + 64);
        float4 s2v = *(const float4*)(base + 128);
        float4 s3 = *(const float4*)(base + 192);
        float4 o;
        o.x = s0.x + s1.x + s2v.x + s3.x;
        o.y = s0.y + s1.y + s2v.y + s3.y;
        o.z = s0.z + s1.z + s2v.z + s3.z;
        o.w = s0.w + s1.w + s2v.w + s3.w;
        *(float4*)(F + idx) = o;
    }
}

// ---------- Kernel BC: S via MFMA + fused pooled partial, 2 b's per block ----------
// grid (32, 16): gx = rpg*2+half, gy = bq (b0 = bq*2). 512 threads = 8 waves.
// wave w: b = b0 + (w&1), rp = rpg*4 + (w>>1). MFMA inner loop == R6.
__global__ void __launch_bounds__(512)
k_bc(const float* __restrict__ CP, const short* __restrict__ WCf,
     const float* __restrict__ F, float* __restrict__ P) {
    int gx   = blockIdx.x;
    int half = gx & 1;
    int rpg  = gx >> 1;              // [0,16)
    int b0   = blockIdx.y * 2;
    int w = threadIdx.x >> 6;        // [0,8)
    int l = threadIdx.x & 63;
    int b_loc  = w & 1;
    int rp_loc = w >> 1;             // [0,4)
    int rp = rpg * 4 + rp_loc;       // [0,64)
    int r0 = rp * 2;
    int b  = b0 + b_loc;

    int i16   = l & 15;
    int r_sel = i16 >> 3;
    int m1    = i16 & 7;
    int lhi   = l >> 4;              // [0,4)

    __shared__ float Stile[2][512];  // [b_loc][j_loc], j_loc = (rp_loc*2+subr)*64 + e

    const float* cp_base = CP + ((size_t)b << 19) + ((size_t)(r0 + r_sel) << 6) + m1 * 8;
    const short8_t* wf   = (const short8_t*)WCf + (size_t)rp * 1024 + (half * 8) * 64 + l;

    f32x4_t acc = {0.f, 0.f, 0.f, 0.f};
    #pragma unroll
    for (int c = 0; c < 8; ++c) {
        int p = (half * 8 + c) * 4 + lhi;
        const float* a_ptr = cp_base + ((size_t)p << 13);   // p*128 rows * 64 floats
        float4 a0 = *(const float4*)(a_ptr);
        float4 a1 = *(const float4*)(a_ptr + 4);
        int4_t ai;
        ai[0] = cvt_pk(a0.x, a0.y);
        ai[1] = cvt_pk(a0.z, a0.w);
        ai[2] = cvt_pk(a1.x, a1.y);
        ai[3] = cvt_pk(a1.z, a1.w);
        acc = __builtin_amdgcn_mfma_f32_16x16x32_bf16(
            __builtin_bit_cast(short8_t, ai), wf[c * 64], acc, 0, 0, 0);
    }
    // C/D layout (m89-verified): col = lane&15, row = (lane>>4)*4 + reg
    int col = i16;
    #pragma unroll
    for (int v = 0; v < 4; ++v) {
        int row = lhi * 4 + v;
        if (row < 8 && col < 8)
            Stile[b_loc][rp_loc * 128 + row * 8 + col] = acc[v];
        else if (row >= 8 && col >= 8)
            Stile[b_loc][rp_loc * 128 + 64 + (row - 8) * 8 + (col - 8)] = acc[v];
    }
    __syncthreads();

    // Pool phase: wave w covers j_loc in [w*64, w*64+64); each F row read once,
    // applied to BOTH b's. lane: g = l>>4 (j within quad), ql = l&15 (q = ql*4+c).
    int g  = l >> 4;
    int ql = l & 15;
    const float* Fb = F + (((size_t)rpg * 512 + w * 64 + g) << 6) + ql * 4;
    f32x4_t p0 = {0.f, 0.f, 0.f, 0.f};
    f32x4_t p1 = {0.f, 0.f, 0.f, 0.f};
    #pragma unroll 4
    for (int s = 0; s < 16; ++s) {
        int jl = w * 64 + s * 4 + g;
        float4 fv = *(const float4*)(Fb + ((size_t)(s * 4) << 6));
        float s0 = Stile[0][jl];
        float s1 = Stile[1][jl];
        p0[0] += s0 * fv.x; p0[1] += s0 * fv.y; p0[2] += s0 * fv.z; p0[3] += s0 * fv.w;
        p1[0] += s1 * fv.x; p1[1] += s1 * fv.y; p1[2] += s1 * fv.z; p1[3] += s1 * fv.w;
    }
    // reduce over g groups (lanes xor 16, 32); lanes 0-15 hold the wave partial
    #pragma unroll
    for (int c = 0; c < 4; ++c) {
        p0[c] += __shfl_xor(p0[c], 16, 64);
        p0[c] += __shfl_xor(p0[c], 32, 64);
        p1[c] += __shfl_xor(p1[c], 16, 64);
        p1[c] += __shfl_xor(p1[c], 32, 64);
    }
    if (l < 16) {
        int sp = (rpg * 2 + half) * 8 + w;      // [0,256) slot per b
        float4 o0; o0.x = p0[0]; o0.y = p0[1]; o0.z = p0[2]; o0.w = p0[3];
        float4 o1; o1.x = p1[0]; o1.y = p1[1]; o1.z = p1[2]; o1.w = p1[3];
        *(float4*)(P + ((size_t)((b0 + 0) * 256 + sp) << 6) + ql * 4) = o0;
        *(float4*)(P + ((size_t)((b0 + 1) * 256 + sp) << 6) + ql * 4) = o1;
    }
}

// ---------- Kernel FINAL ----------
// grid (32): b. pooled[b,q] = (1/64)*sum_{sp<256} P[b][sp][q]; epilogue GEMM.
__global__ void k_final(const float* __restrict__ P, const float* __restrict__ rel,
                        const float* __restrict__ WN, float* __restrict__ out) {
    int b  = blockIdx.x;
    int t  = threadIdx.x;
    int q    = t & 63;
    int sgrp = t >> 6;               // [0,4): 64 slots each
    const float* Pb = P + ((size_t)b << 14);   // 256 slots * 64
    float s = 0.f;
    #pragma unroll 8
    for (int c = sgrp * 64; c < sgrp * 64 + 64; ++c)
        s += Pb[((size_t)c << 6) + q];
    __shared__ float red[4][64];
    red[sgrp][q] = s;
    __syncthreads();
    __shared__ float pool_s[64];
    if (t < 64) {
        pool_s[t] = (red[0][t] + red[1][t] + red[2][t] + red[3][t]) * (1.0f / 64.0f)
                    + rel[t];
    }
    __syncthreads();
    #pragma unroll
    for (int idx = t; idx < 4096; idx += 256) {
        int o = idx >> 6;
        int e = idx & 63;
        int m1 = e >> 3, m2 = e & 7;
        float a = 0.f;
        #pragma unroll
        for (int k = 0; k < 8; ++k)
            a += pool_s[m1 * 8 + k] * WN[o * 64 + k * 8 + m2];
        out[((size_t)b << 12) + idx] = a;
    }
}

extern "C" void kernel_launch(void* const* d_in, const int* in_sizes, int n_in,
                              void* d_out, int out_size, void* d_ws, size_t ws_size,
                              hipStream_t stream) {
    const float* current_pose = (const float*)d_in[0];  // (32, 8192, 64)
    const float* w_current    = (const float*)d_in[1];  // (1,1,8192,8,8)
    const float* w_next       = (const float*)d_in[2];  // (64,8,8)
    const float* E_proj       = (const float*)d_in[3];  // (32,256,256)
    const float* rel_embedd   = (const float*)d_in[4];  // (1,1,64)
    float* out = (float*)d_out;                         // (32,1,64,64)

    char* ws = (char*)d_ws;
    float* F   = (float*)(ws);                    // 2 MiB
    short* WCf = (short*)(ws + (2u << 20));       // 1 MiB
    float* P   = (float*)(ws + (3u << 20));       // 2 MiB (32 x 256 x 64)

    // PREP: WCf pack (256 blocks) + E fold (512 blocks)
    k_prep<<<dim3(768), dim3(256), 0, stream>>>(w_current, WCf, E_proj, F);
    // BC: MFMA S-slices + fused pooled partials, 2 b's per block (F amp halved)
    k_bc<<<dim3(32, 16), dim3(512), 0, stream>>>(current_pose, WCf, F, P);
    // FINAL
    k_final<<<dim3(32), dim3(256), 0, stream>>>(P, rel_embedd, w_next, out);
}